// Round 4
// baseline (230.878 us; speedup 1.0000x reference)
//
#include <hip/hip_runtime.h>
#include <stdint.h>

#define NT 256
#define RPB 16
#define XSTR 80            // byte stride between k-slots (20 floats, 16B-aligned, bank-staggered)

// ws layout (byte offsets)
#define WS_TAB   0
#define TB_P3    0         // 512 x ushort4 {o0,o1,o2, c3_bf16}
#define TB_P4    4096      // 512 x ushort4 {o0..o3}
#define TB_P5    8192      // 512 x ushort4 {o0..o3}
#define TB_P5E   12288     // 512 x ushort  {o4}
#define TB_C4    13312     // 512 x ushort  c4 bf16
#define TB_C5    14336     // 512 x ushort  c5 bf16
#define TB_SZ    15360
#define WS_BUT   15360     // 4096 floats buT[j][i] = (i<j)? b[i][j] : 0
#define WS_CGCOL 31744     // 64 x int   (active col4 group ids, padded)
#define WS_CGSL  32000     // 64 x short4 (prescaled byte offsets, -1 = none)
#define WS_LEAD  32512     // 64 x short (duplicate-run leader per k)

static __device__ __forceinline__ unsigned short f2bf(float f) {
    unsigned u = __float_as_uint(f);
    return (unsigned short)((u + 0x7FFFu + ((u >> 16) & 1u)) >> 16);
}
static __device__ __forceinline__ float bf2f(unsigned short h) {
    return __uint_as_float((unsigned)h << 16);
}
static __device__ __forceinline__ float4 f4fma(float s, float4 v, float4 acc) {
    acc.x += s * v.x; acc.y += s * v.y; acc.z += s * v.z; acc.w += s * v.w;
    return acc;
}

__global__ void prepack(const int* __restrict__ S, const float* __restrict__ b,
                        const int* __restrict__ i3, const float* __restrict__ c3,
                        const int* __restrict__ i4, const float* __restrict__ c4,
                        const int* __restrict__ i5, const float* __restrict__ c5,
                        unsigned char* __restrict__ ws)
{
    __shared__ short slotS[1024];
    __shared__ int cnt;
    const int tid = threadIdx.x;
    for (int e = tid; e < 1024; e += NT) slotS[e] = -1;
    if (tid == 0) cnt = 0;
    __syncthreads();
    if (tid < 64) {
        int sv = S[tid];
        int k0 = tid;
        while (k0 > 0 && S[k0 - 1] == sv) --k0;       // duplicate-run leader
        ((short*)(ws + WS_LEAD))[tid] = (short)k0;
        if (k0 == tid) slotS[sv] = (short)tid;        // unique writer per column
    }
    __syncthreads();
    int* cgcol = (int*)(ws + WS_CGCOL);
    short4* cgsl = (short4*)(ws + WS_CGSL);
    {
        int g = tid;  // 256 col4 groups
        short s0 = slotS[4*g], s1 = slotS[4*g+1], s2 = slotS[4*g+2], s3 = slotS[4*g+3];
        if (s0 >= 0 || s1 >= 0 || s2 >= 0 || s3 >= 0) {
            int pos = atomicAdd(&cnt, 1);
            cgcol[pos] = g;
            cgsl[pos] = make_short4(s0 >= 0 ? (short)(s0 * XSTR) : (short)-1,
                                    s1 >= 0 ? (short)(s1 * XSTR) : (short)-1,
                                    s2 >= 0 ? (short)(s2 * XSTR) : (short)-1,
                                    s3 >= 0 ? (short)(s3 * XSTR) : (short)-1);
        }
    }
    __syncthreads();
    if (tid == 0) {
        for (int p = cnt; p < 64; ++p) {
            cgcol[p] = 0;
            cgsl[p] = make_short4(-1, -1, -1, -1);
        }
    }
    float* buT = (float*)(ws + WS_BUT);
    for (int e = tid; e < 4096; e += NT) {
        int j = e >> 6, i = e & 63;
        buT[e] = (i < j) ? b[i * 64 + j] : 0.0f;     // transposed strict-upper
    }
    ushort4* p3 = (ushort4*)(ws + TB_P3);
    ushort4* p4 = (ushort4*)(ws + TB_P4);
    ushort4* p5 = (ushort4*)(ws + TB_P5);
    unsigned short* p5e = (unsigned short*)(ws + TB_P5E);
    unsigned short* c4h = (unsigned short*)(ws + TB_C4);
    unsigned short* c5h = (unsigned short*)(ws + TB_C5);
    for (int t = tid; t < 512; t += NT) {
        p3[t] = make_ushort4((unsigned short)(i3[3*t+0]*XSTR), (unsigned short)(i3[3*t+1]*XSTR),
                             (unsigned short)(i3[3*t+2]*XSTR), f2bf(c3[t]));
        p4[t] = make_ushort4((unsigned short)(i4[4*t+0]*XSTR), (unsigned short)(i4[4*t+1]*XSTR),
                             (unsigned short)(i4[4*t+2]*XSTR), (unsigned short)(i4[4*t+3]*XSTR));
        p5[t] = make_ushort4((unsigned short)(i5[5*t+0]*XSTR), (unsigned short)(i5[5*t+1]*XSTR),
                             (unsigned short)(i5[5*t+2]*XSTR), (unsigned short)(i5[5*t+3]*XSTR));
        p5e[t] = (unsigned short)(i5[5*t+4]*XSTR);
        c4h[t] = f2bf(c4[t]);
        c5h[t] = f2bf(c5[t]);
    }
}

// LDS: 5120 (xS) + 15360 (tables) + 256 (red) = 20736 B -> ~6 blocks/CU at 24 waves/CU
__global__ __launch_bounds__(NT, 6)
void poly_main(const float* __restrict__ x, const float* __restrict__ a,
               const unsigned char* __restrict__ ws, float* __restrict__ out)
{
    __shared__ float xS[64 * 20];          // [k][row0..15 + pad], 80B stride
    __shared__ unsigned char tabL[TB_SZ];
    __shared__ float red[64];              // [wave][row] partials

    const int tid  = threadIdx.x;
    const int row0 = blockIdx.x * RPB;

    // ---- tables ws -> LDS (coalesced uint4) ----
    {
        const uint4* src = (const uint4*)(ws + WS_TAB);
        uint4* dst = (uint4*)tabL;
        for (int e = tid; e < TB_SZ / 16; e += NT) dst[e] = src[e];
    }
    // ---- stage x: dense compacted gather, 4 loads/thread ----
    {
        const int g = tid & 63, rs = tid >> 6;
        int col4 = ((const int*)(ws + WS_CGCOL))[g];
        short4 sl = ((const short4*)(ws + WS_CGSL))[g];
        if (sl.x >= 0 || sl.y >= 0 || sl.z >= 0 || sl.w >= 0) {
            const float4* Xrow = (const float4*)(x + (size_t)row0 * 1024);
            char* xsb = (char*)xS;
            #pragma unroll
            for (int m = 0; m < 4; ++m) {
                int r = rs * 4 + m;
                float4 v = Xrow[r * 256 + col4];
                int rb = r * 4;
                if (sl.x >= 0) *(float*)(xsb + sl.x + rb) = v.x;
                if (sl.y >= 0) *(float*)(xsb + sl.y + rb) = v.y;
                if (sl.z >= 0) *(float*)(xsb + sl.z + rb) = v.z;
                if (sl.w >= 0) *(float*)(xsb + sl.w + rb) = v.w;
            }
        }
    }
    __syncthreads();
    // ---- replicate duplicated columns from run leader ----
    {
        int k = tid >> 2, q = tid & 3;
        int k0 = ((const short*)(ws + WS_LEAD))[k];
        if (k0 != k) {
            float4* dst = (float4*)((char*)xS + k  * XSTR);
            const float4* src = (const float4*)((char*)xS + k0 * XSTR);
            dst[q] = src[q];
        }
    }
    __syncthreads();

    // ---- compute: rg owns rows 4rg..4rg+3 (float4), ts = j / term slice (0..63) ----
    const int rg = tid & 3;
    const int ts = tid >> 2;
    const char* xb = (const char*)xS + rg * 16;

    // quad (triangular): d_e = sum_{i<ts} buT[ts][i] * x_i[e]
    float4 d = make_float4(0.f, 0.f, 0.f, 0.f);
    {
        const float4* buT4 = (const float4*)(ws + WS_BUT) + ts * 16;
        const int nii = (ts + 3) >> 2;             // zeros in buT mask the partial group
        #pragma unroll 4
        for (int ii = 0; ii < nii; ++ii) {
            float4 bb  = buT4[ii];
            float4 xi0 = *(const float4*)(xb + (ii * 4 + 0) * XSTR);
            float4 xi1 = *(const float4*)(xb + (ii * 4 + 1) * XSTR);
            float4 xi2 = *(const float4*)(xb + (ii * 4 + 2) * XSTR);
            float4 xi3 = *(const float4*)(xb + (ii * 4 + 3) * XSTR);
            d = f4fma(bb.x, xi0, d);
            d = f4fma(bb.y, xi1, d);
            d = f4fma(bb.z, xi2, d);
            d = f4fma(bb.w, xi3, d);
        }
    }
    float av = a[ts];
    float4 xj = *(const float4*)(xb + ts * XSTR);
    float4 acc;
    acc.x = (av + d.x) * xj.x;
    acc.y = (av + d.y) * xj.y;
    acc.z = (av + d.z) * xj.z;
    acc.w = (av + d.w) * xj.w;

    // ---- monomials: term t = 64*m + ts, 8 per degree per thread ----
    const ushort4* p3L = (const ushort4*)(tabL + TB_P3);
    const ushort4* p4L = (const ushort4*)(tabL + TB_P4);
    const ushort4* p5L = (const ushort4*)(tabL + TB_P5);
    const unsigned short* p5eL = (const unsigned short*)(tabL + TB_P5E);
    const unsigned short* c4L  = (const unsigned short*)(tabL + TB_C4);
    const unsigned short* c5L  = (const unsigned short*)(tabL + TB_C5);

    #pragma unroll 4
    for (int m = 0; m < 8; ++m) {
        ushort4 p = p3L[64 * m + ts];
        float4 v0 = *(const float4*)(xb + p.x);
        float4 v1 = *(const float4*)(xb + p.y);
        float4 v2 = *(const float4*)(xb + p.z);
        float c = bf2f(p.w);
        acc.x += c * ((v0.x * v1.x) * v2.x);
        acc.y += c * ((v0.y * v1.y) * v2.y);
        acc.z += c * ((v0.z * v1.z) * v2.z);
        acc.w += c * ((v0.w * v1.w) * v2.w);
    }
    #pragma unroll 2
    for (int m = 0; m < 8; ++m) {
        int t = 64 * m + ts;
        ushort4 p = p4L[t];
        float c = bf2f(c4L[t]);
        float4 v0 = *(const float4*)(xb + p.x);
        float4 v1 = *(const float4*)(xb + p.y);
        float4 v2 = *(const float4*)(xb + p.z);
        float4 v3 = *(const float4*)(xb + p.w);
        acc.x += c * ((v0.x * v1.x) * (v2.x * v3.x));
        acc.y += c * ((v0.y * v1.y) * (v2.y * v3.y));
        acc.z += c * ((v0.z * v1.z) * (v2.z * v3.z));
        acc.w += c * ((v0.w * v1.w) * (v2.w * v3.w));
    }
    #pragma unroll 2
    for (int m = 0; m < 8; ++m) {
        int t = 64 * m + ts;
        ushort4 p = p5L[t];
        int o4 = p5eL[t];
        float c = bf2f(c5L[t]);
        float4 v0 = *(const float4*)(xb + p.x);
        float4 v1 = *(const float4*)(xb + p.y);
        float4 v2 = *(const float4*)(xb + p.z);
        float4 v3 = *(const float4*)(xb + p.w);
        float4 v4 = *(const float4*)(xb + o4);
        acc.x += c * (((v0.x * v1.x) * (v2.x * v3.x)) * v4.x);
        acc.y += c * (((v0.y * v1.y) * (v2.y * v3.y)) * v4.y);
        acc.z += c * (((v0.z * v1.z) * (v2.z * v3.z)) * v4.z);
        acc.w += c * (((v0.w * v1.w) * (v2.w * v3.w)) * v4.w);
    }

    // ---- reduce 16 ts-partials within wave (lanes same rg differ in bits 2..5) ----
    #pragma unroll
    for (int mask = 4; mask <= 32; mask <<= 1) {
        acc.x += __shfl_xor(acc.x, mask, 64);
        acc.y += __shfl_xor(acc.y, mask, 64);
        acc.z += __shfl_xor(acc.z, mask, 64);
        acc.w += __shfl_xor(acc.w, mask, 64);
    }
    const int w = tid >> 6;
    const int lane = tid & 63;
    if (lane < 4) ((float4*)red)[w * 4 + lane] = acc;
    __syncthreads();
    if (tid < 16) {
        float s = red[tid] + red[16 + tid] + red[32 + tid] + red[48 + tid];
        out[row0 + tid] = s;
    }
}

extern "C" void kernel_launch(void* const* d_in, const int* in_sizes, int n_in,
                              void* d_out, int out_size, void* d_ws, size_t ws_size,
                              hipStream_t stream) {
    const float* x  = (const float*)d_in[0];
    const int*   S  = (const int*)d_in[1];
    const float* a  = (const float*)d_in[2];
    const float* b  = (const float*)d_in[3];
    const int*   i3 = (const int*)d_in[4];
    const float* c3 = (const float*)d_in[5];
    const int*   i4 = (const int*)d_in[6];
    const float* c4 = (const float*)d_in[7];
    const int*   i5 = (const int*)d_in[8];
    const float* c5 = (const float*)d_in[9];
    unsigned char* ws = (unsigned char*)d_ws;
    float* out = (float*)d_out;

    prepack<<<1, NT, 0, stream>>>(S, b, i3, c3, i4, c4, i5, c5, ws);
    poly_main<<<32768 / RPB, NT, 0, stream>>>(x, a, ws, out);
}

// Round 5
// 213.308 us; speedup vs baseline: 1.0824x; 1.0824x over previous
//
#include <hip/hip_runtime.h>
#include <stdint.h>

#define NT 256
#define RPB 16
#define XSTR 80            // bytes between k-slots (20 floats; 16B-aligned, odd/16 -> 8 bank classes)

// ws layout (byte offsets)
#define WS_P3   0          // 512 x 8B  {o0,o1,o2, c3_bf16}
#define WS_P4   4096       // 512 x 16B {o0,o1 | o2,o3 | c4_bf16,0 | 0}
#define WS_P5   12288      // 512 x 16B {o0,o1 | o2,o3 | o4,c5_bf16 | 0}
#define WS_BUT  20480      // 4096 floats buT[j][i] = (i<j) ? b[i][j] : 0

static __device__ __forceinline__ unsigned short f2bf(float f) {
    unsigned u = __float_as_uint(f);
    return (unsigned short)((u + 0x7FFFu + ((u >> 16) & 1u)) >> 16);
}
static __device__ __forceinline__ float bfbits(unsigned lo16) {   // low 16 bits -> float
    return __uint_as_float(lo16 << 16);
}
static __device__ __forceinline__ float4 f4fma(float s, float4 v, float4 acc) {
    acc.x += s * v.x; acc.y += s * v.y; acc.z += s * v.z; acc.w += s * v.w;
    return acc;
}

__global__ void prepack(const float* __restrict__ b,
                        const int* __restrict__ i3, const float* __restrict__ c3,
                        const int* __restrict__ i4, const float* __restrict__ c4,
                        const int* __restrict__ i5, const float* __restrict__ c5,
                        unsigned char* __restrict__ ws)
{
    const int g = blockIdx.x * NT + threadIdx.x;   // 16 blocks x 256 = 4096 threads
    float* buT = (float*)(ws + WS_BUT);
    if (g < 4096) {
        int j = g >> 6, i = g & 63;
        buT[g] = (i < j) ? b[i * 64 + j] : 0.0f;   // transposed strict-upper
    }
    if (g < 512) {
        unsigned o0, o1, o2, o3, o4;
        // deg3: 8B entry {o0,o1,o2,c3}
        o0 = (unsigned)i3[3*g+0] * XSTR; o1 = (unsigned)i3[3*g+1] * XSTR; o2 = (unsigned)i3[3*g+2] * XSTR;
        ((uint2*)(ws + WS_P3))[g] = make_uint2(o0 | (o1 << 16), o2 | ((unsigned)f2bf(c3[g]) << 16));
        // deg4: 16B entry
        o0 = (unsigned)i4[4*g+0] * XSTR; o1 = (unsigned)i4[4*g+1] * XSTR;
        o2 = (unsigned)i4[4*g+2] * XSTR; o3 = (unsigned)i4[4*g+3] * XSTR;
        ((uint4*)(ws + WS_P4))[g] = make_uint4(o0 | (o1 << 16), o2 | (o3 << 16), (unsigned)f2bf(c4[g]), 0u);
        // deg5: 16B entry
        o0 = (unsigned)i5[5*g+0] * XSTR; o1 = (unsigned)i5[5*g+1] * XSTR;
        o2 = (unsigned)i5[5*g+2] * XSTR; o3 = (unsigned)i5[5*g+3] * XSTR;
        o4 = (unsigned)i5[5*g+4] * XSTR;
        ((uint4*)(ws + WS_P5))[g] = make_uint4(o0 | (o1 << 16), o2 | (o3 << 16), o4 | ((unsigned)f2bf(c5[g]) << 16), 0u);
    }
}

// LDS: 5120 (xS) + 256 (red) = 5376 B. Occupancy bounded by VGPR only.
__global__ __launch_bounds__(NT, 4)
void poly_main(const float* __restrict__ x, const int* __restrict__ S,
               const float* __restrict__ a,
               const unsigned char* __restrict__ ws, float* __restrict__ out)
{
    __shared__ __align__(16) float xS[64 * 20];    // [k][16 rows + 4 pad]
    __shared__ float red[64];                      // [wave][rg][e]

    const int tid  = threadIdx.x;
    const int row0 = blockIdx.x * RPB;

    // ---- stage: direct per-k gather (S sorted -> line-clustered); dups handled naturally ----
    {
        const int k = tid & 63, q = tid >> 6;      // wave q loads rows 4q..4q+3
        const int sk = S[k];
        const float* xc = x + (size_t)row0 * 1024 + sk;
        #pragma unroll
        for (int m = 0; m < 4; ++m) {
            int r = q * 4 + m;
            xS[k * 20 + r] = xc[(size_t)r * 1024];
        }
    }
    __syncthreads();

    // ---- compute: rg owns rows 4rg..4rg+3 (float4), ts = j / term slice (0..63) ----
    const int rg = tid & 3;
    const int ts = tid >> 2;
    const char* xb = (const char*)xS + rg * 16;

    // quad (triangular): d_e = sum_{i<ts} buT[ts][i] * x_i[e]; buT zeros mask the partial group
    float4 d = make_float4(0.f, 0.f, 0.f, 0.f);
    {
        const float4* buT4 = (const float4*)(ws + WS_BUT) + ts * 16;
        const int nii = (ts + 3) >> 2;
        #pragma unroll 4
        for (int ii = 0; ii < nii; ++ii) {
            float4 bb  = buT4[ii];
            float4 xi0 = *(const float4*)(xb + (ii * 4 + 0) * XSTR);
            float4 xi1 = *(const float4*)(xb + (ii * 4 + 1) * XSTR);
            float4 xi2 = *(const float4*)(xb + (ii * 4 + 2) * XSTR);
            float4 xi3 = *(const float4*)(xb + (ii * 4 + 3) * XSTR);
            d = f4fma(bb.x, xi0, d);
            d = f4fma(bb.y, xi1, d);
            d = f4fma(bb.z, xi2, d);
            d = f4fma(bb.w, xi3, d);
        }
    }
    const float av = a[ts];
    float4 xj = *(const float4*)(xb + ts * XSTR);
    float4 acc;
    acc.x = (av + d.x) * xj.x;
    acc.y = (av + d.y) * xj.y;
    acc.z = (av + d.z) * xj.z;
    acc.w = (av + d.w) * xj.w;

    // ---- monomials: term t = 64*m + ts, 8 per degree; tables via VMEM (L1-resident) ----
    const uint2* p3 = (const uint2*)(ws + WS_P3);
    const uint4* p4 = (const uint4*)(ws + WS_P4);
    const uint4* p5 = (const uint4*)(ws + WS_P5);

    #pragma unroll 4
    for (int m = 0; m < 8; ++m) {
        uint2 p = p3[64 * m + ts];
        float4 v0 = *(const float4*)(xb + (p.x & 0xFFFFu));
        float4 v1 = *(const float4*)(xb + (p.x >> 16));
        float4 v2 = *(const float4*)(xb + (p.y & 0xFFFFu));
        float c = bfbits(p.y >> 16);
        acc.x += c * ((v0.x * v1.x) * v2.x);
        acc.y += c * ((v0.y * v1.y) * v2.y);
        acc.z += c * ((v0.z * v1.z) * v2.z);
        acc.w += c * ((v0.w * v1.w) * v2.w);
    }
    #pragma unroll 4
    for (int m = 0; m < 8; ++m) {
        uint4 p = p4[64 * m + ts];
        float4 v0 = *(const float4*)(xb + (p.x & 0xFFFFu));
        float4 v1 = *(const float4*)(xb + (p.x >> 16));
        float4 v2 = *(const float4*)(xb + (p.y & 0xFFFFu));
        float4 v3 = *(const float4*)(xb + (p.y >> 16));
        float c = bfbits(p.z & 0xFFFFu);
        acc.x += c * ((v0.x * v1.x) * (v2.x * v3.x));
        acc.y += c * ((v0.y * v1.y) * (v2.y * v3.y));
        acc.z += c * ((v0.z * v1.z) * (v2.z * v3.z));
        acc.w += c * ((v0.w * v1.w) * (v2.w * v3.w));
    }
    #pragma unroll 4
    for (int m = 0; m < 8; ++m) {
        uint4 p = p5[64 * m + ts];
        float4 v0 = *(const float4*)(xb + (p.x & 0xFFFFu));
        float4 v1 = *(const float4*)(xb + (p.x >> 16));
        float4 v2 = *(const float4*)(xb + (p.y & 0xFFFFu));
        float4 v3 = *(const float4*)(xb + (p.y >> 16));
        float4 v4 = *(const float4*)(xb + (p.z & 0xFFFFu));
        float c = bfbits(p.z >> 16);
        acc.x += c * (((v0.x * v1.x) * (v2.x * v3.x)) * v4.x);
        acc.y += c * (((v0.y * v1.y) * (v2.y * v3.y)) * v4.y);
        acc.z += c * (((v0.z * v1.z) * (v2.z * v3.z)) * v4.z);
        acc.w += c * (((v0.w * v1.w) * (v2.w * v3.w)) * v4.w);
    }

    // ---- reduce 16 ts-partials within wave (ts low bits = lane bits 2..5) ----
    #pragma unroll
    for (int mask = 4; mask <= 32; mask <<= 1) {
        acc.x += __shfl_xor(acc.x, mask, 64);
        acc.y += __shfl_xor(acc.y, mask, 64);
        acc.z += __shfl_xor(acc.z, mask, 64);
        acc.w += __shfl_xor(acc.w, mask, 64);
    }
    const int w = tid >> 6, lane = tid & 63;
    if (lane < 4) ((float4*)red)[w * 4 + lane] = acc;
    __syncthreads();
    if (tid < 16) {
        out[row0 + tid] = red[tid] + red[16 + tid] + red[32 + tid] + red[48 + tid];
    }
}

extern "C" void kernel_launch(void* const* d_in, const int* in_sizes, int n_in,
                              void* d_out, int out_size, void* d_ws, size_t ws_size,
                              hipStream_t stream) {
    const float* x  = (const float*)d_in[0];
    const int*   S  = (const int*)d_in[1];
    const float* a  = (const float*)d_in[2];
    const float* b  = (const float*)d_in[3];
    const int*   i3 = (const int*)d_in[4];
    const float* c3 = (const float*)d_in[5];
    const int*   i4 = (const int*)d_in[6];
    const float* c4 = (const float*)d_in[7];
    const int*   i5 = (const int*)d_in[8];
    const float* c5 = (const float*)d_in[9];
    unsigned char* ws = (unsigned char*)d_ws;
    float* out = (float*)d_out;

    prepack<<<16, NT, 0, stream>>>(b, i3, c3, i4, c4, i5, c5, ws);
    poly_main<<<32768 / RPB, NT, 0, stream>>>(x, S, a, ws, out);
}

// Round 6
// 210.103 us; speedup vs baseline: 1.0989x; 1.0153x over previous
//
#include <hip/hip_runtime.h>
#include <hip/hip_fp16.h>
#include <stdint.h>

#define NT 256
#define RPB 32             // rows per block
#define XSTR 80            // bytes per k-slot: 40 halfs (32 rows + 8 pad), 16B-aligned

// ws layout (byte offsets)
#define WS_P3   0          // 512 x 8B  {o0|o1<<16, o2|c3h<<16}
#define WS_P4   4096       // 512 x 16B {o0|o1, o2|o3, c4h, 0}
#define WS_P5   12288      // 512 x 16B {o0|o1, o2|o3, o4|c5h, 0}
#define WS_BUTH 20480      // 64x64 halfs: buTh[j][i] = (i<j) ? half(b[i][j]) : 0

static __device__ __forceinline__ __half2 H2(unsigned u) {
    return __builtin_bit_cast(__half2, u);
}
static __device__ __forceinline__ unsigned short f2hbits(float f) {
    __half h = __float2half(f);
    return __builtin_bit_cast(unsigned short, h);
}

__global__ void prepack(const float* __restrict__ b,
                        const int* __restrict__ i3, const float* __restrict__ c3,
                        const int* __restrict__ i4, const float* __restrict__ c4,
                        const int* __restrict__ i5, const float* __restrict__ c5,
                        unsigned char* __restrict__ ws)
{
    const int g = blockIdx.x * NT + threadIdx.x;   // 16 x 256 = 4096
    if (g < 4096) {
        int j = g >> 6, i = g & 63;
        float v = (i < j) ? b[i * 64 + j] : 0.0f;  // transposed strict-upper
        ((unsigned short*)(ws + WS_BUTH))[g] = f2hbits(v);
    }
    if (g < 512) {
        unsigned o0, o1, o2, o3, o4;
        o0 = (unsigned)i3[3*g+0] * XSTR; o1 = (unsigned)i3[3*g+1] * XSTR; o2 = (unsigned)i3[3*g+2] * XSTR;
        ((uint2*)(ws + WS_P3))[g] = make_uint2(o0 | (o1 << 16), o2 | ((unsigned)f2hbits(c3[g]) << 16));
        o0 = (unsigned)i4[4*g+0] * XSTR; o1 = (unsigned)i4[4*g+1] * XSTR;
        o2 = (unsigned)i4[4*g+2] * XSTR; o3 = (unsigned)i4[4*g+3] * XSTR;
        ((uint4*)(ws + WS_P4))[g] = make_uint4(o0 | (o1 << 16), o2 | (o3 << 16), (unsigned)f2hbits(c4[g]), 0u);
        o0 = (unsigned)i5[5*g+0] * XSTR; o1 = (unsigned)i5[5*g+1] * XSTR;
        o2 = (unsigned)i5[5*g+2] * XSTR; o3 = (unsigned)i5[5*g+3] * XSTR;
        o4 = (unsigned)i5[5*g+4] * XSTR;
        ((uint4*)(ws + WS_P5))[g] = make_uint4(o0 | (o1 << 16), o2 | (o3 << 16), o4 | ((unsigned)f2hbits(c5[g]) << 16), 0u);
    }
}

static __device__ __forceinline__ void qfma(__half2 bb, uint4 xk, __half2 d[4]) {
    d[0] = __hfma2(bb, H2(xk.x), d[0]);
    d[1] = __hfma2(bb, H2(xk.y), d[1]);
    d[2] = __hfma2(bb, H2(xk.z), d[2]);
    d[3] = __hfma2(bb, H2(xk.w), d[3]);
}
static __device__ __forceinline__ void pmul(const uint4& a, __half2 p[4]) {
    p[0] = __hmul2(p[0], H2(a.x));
    p[1] = __hmul2(p[1], H2(a.y));
    p[2] = __hmul2(p[2], H2(a.z));
    p[3] = __hmul2(p[3], H2(a.w));
}
static __device__ __forceinline__ void pacc(__half2 c2, const __half2 p[4], __half2 acc[4]) {
    acc[0] = __hfma2(c2, p[0], acc[0]);
    acc[1] = __hfma2(c2, p[1], acc[1]);
    acc[2] = __hfma2(c2, p[2], acc[2]);
    acc[3] = __hfma2(c2, p[3], acc[3]);
}

// LDS: 5120 (xS fp16) + 512 (red) = 5632 B. 1024 blocks -> 4 blocks/CU, 16 waves/CU.
__global__ __launch_bounds__(NT, 4)
void poly_main(const float* __restrict__ x, const int* __restrict__ S,
               const float* __restrict__ a,
               const unsigned char* __restrict__ ws, float* __restrict__ out)
{
    __shared__ __align__(16) __half xS[64 * 40];   // [k][32 rows (fp16) + 8 pad]
    __shared__ float red[4][4][8];                 // [wave][rg][row-in-group]

    const int tid  = threadIdx.x;
    const int row0 = blockIdx.x * RPB;

    // ---- gather + fp16 pack: lane k, wave q loads rows q*8..q*8+7 ----
    {
        const int k = tid & 63, q = tid >> 6;
        const int sk = S[k];
        const float* xc = x + (size_t)row0 * 1024 + sk;
        float v[8];
        #pragma unroll
        for (int m = 0; m < 8; ++m) v[m] = xc[(size_t)(q * 8 + m) * 1024];
        uint4 pk;
        pk.x = __builtin_bit_cast(unsigned, __floats2half2_rn(v[0], v[1]));
        pk.y = __builtin_bit_cast(unsigned, __floats2half2_rn(v[2], v[3]));
        pk.z = __builtin_bit_cast(unsigned, __floats2half2_rn(v[4], v[5]));
        pk.w = __builtin_bit_cast(unsigned, __floats2half2_rn(v[6], v[7]));
        *(uint4*)((char*)xS + k * XSTR + q * 16) = pk;
    }
    __syncthreads();

    // ---- compute: rg owns rows rg*8..rg*8+7 (4 half2), ts = j / term slice (0..63) ----
    const int rg = tid & 3;
    const int ts = tid >> 2;
    const char* xb = (const char*)xS + rg * 16;

    // quad (triangular): d = sum_{i<ts} buT[ts][i] * x_i ; zeros mask the partial group
    __half2 d[4] = {H2(0u), H2(0u), H2(0u), H2(0u)};
    {
        const uint4* buTh4 = (const uint4*)(ws + WS_BUTH) + ts * 8;  // row ts: 64 halfs
        const int nii = (ts + 7) >> 3;
        #pragma unroll 2
        for (int g = 0; g < nii; ++g) {
            uint4 bw = buTh4[g];
            const char* xkb = xb + g * 8 * XSTR;
            unsigned pw[4] = {bw.x, bw.y, bw.z, bw.w};
            #pragma unroll
            for (int p = 0; p < 4; ++p) {
                __half2 blo = __half2half2(__ushort_as_half((unsigned short)(pw[p] & 0xFFFFu)));
                __half2 bhi = __half2half2(__ushort_as_half((unsigned short)(pw[p] >> 16)));
                uint4 x0 = *(const uint4*)(xkb + (2 * p + 0) * XSTR);
                uint4 x1 = *(const uint4*)(xkb + (2 * p + 1) * XSTR);
                qfma(blo, x0, d);
                qfma(bhi, x1, d);
            }
        }
    }
    __half2 acc[4];
    {
        __half2 a2 = __half2half2(__float2half(a[ts]));
        uint4 xj = *(const uint4*)(xb + ts * XSTR);
        acc[0] = __hmul2(__hadd2(a2, d[0]), H2(xj.x));
        acc[1] = __hmul2(__hadd2(a2, d[1]), H2(xj.y));
        acc[2] = __hmul2(__hadd2(a2, d[2]), H2(xj.z));
        acc[3] = __hmul2(__hadd2(a2, d[3]), H2(xj.w));
    }

    // ---- monomials: term t = 64*m + ts, 8 per degree; tables via VMEM (L1-resident) ----
    const uint2* p3 = (const uint2*)(ws + WS_P3);
    const uint4* p4 = (const uint4*)(ws + WS_P4);
    const uint4* p5 = (const uint4*)(ws + WS_P5);

    #pragma unroll 4
    for (int m = 0; m < 8; ++m) {
        uint2 p = p3[64 * m + ts];
        uint4 v0 = *(const uint4*)(xb + (p.x & 0xFFFFu));
        uint4 v1 = *(const uint4*)(xb + (p.x >> 16));
        uint4 v2 = *(const uint4*)(xb + (p.y & 0xFFFFu));
        __half2 pr[4] = {H2(v0.x), H2(v0.y), H2(v0.z), H2(v0.w)};
        pmul(v1, pr);
        pmul(v2, pr);
        pacc(__half2half2(__ushort_as_half((unsigned short)(p.y >> 16))), pr, acc);
    }
    #pragma unroll 2
    for (int m = 0; m < 8; ++m) {
        uint4 p = p4[64 * m + ts];
        uint4 v0 = *(const uint4*)(xb + (p.x & 0xFFFFu));
        uint4 v1 = *(const uint4*)(xb + (p.x >> 16));
        uint4 v2 = *(const uint4*)(xb + (p.y & 0xFFFFu));
        uint4 v3 = *(const uint4*)(xb + (p.y >> 16));
        __half2 pr[4] = {H2(v0.x), H2(v0.y), H2(v0.z), H2(v0.w)};
        pmul(v1, pr);
        pmul(v2, pr);
        pmul(v3, pr);
        pacc(__half2half2(__ushort_as_half((unsigned short)(p.z & 0xFFFFu))), pr, acc);
    }
    #pragma unroll 2
    for (int m = 0; m < 8; ++m) {
        uint4 p = p5[64 * m + ts];
        uint4 v0 = *(const uint4*)(xb + (p.x & 0xFFFFu));
        uint4 v1 = *(const uint4*)(xb + (p.x >> 16));
        uint4 v2 = *(const uint4*)(xb + (p.y & 0xFFFFu));
        uint4 v3 = *(const uint4*)(xb + (p.y >> 16));
        uint4 v4 = *(const uint4*)(xb + (p.z & 0xFFFFu));
        __half2 pr[4] = {H2(v0.x), H2(v0.y), H2(v0.z), H2(v0.w)};
        pmul(v1, pr);
        pmul(v2, pr);
        pmul(v3, pr);
        pmul(v4, pr);
        pacc(__half2half2(__ushort_as_half((unsigned short)(p.z >> 16))), pr, acc);
    }

    // ---- reduce 16 ts-partials per wave in fp32, then cross-wave via LDS ----
    float f[8];
    #pragma unroll
    for (int e = 0; e < 4; ++e) {
        f[2 * e]     = __low2float(acc[e]);
        f[2 * e + 1] = __high2float(acc[e]);
    }
    #pragma unroll
    for (int mask = 4; mask <= 32; mask <<= 1) {
        #pragma unroll
        for (int r = 0; r < 8; ++r) f[r] += __shfl_xor(f[r], mask, 64);
    }
    const int w = tid >> 6, lane = tid & 63;
    if (lane < 4) {
        #pragma unroll
        for (int r = 0; r < 8; ++r) red[w][lane][r] = f[r];
    }
    __syncthreads();
    if (tid < 32) {
        int g = tid >> 3, e = tid & 7;
        out[row0 + tid] = red[0][g][e] + red[1][g][e] + red[2][g][e] + red[3][g][e];
    }
}

extern "C" void kernel_launch(void* const* d_in, const int* in_sizes, int n_in,
                              void* d_out, int out_size, void* d_ws, size_t ws_size,
                              hipStream_t stream) {
    const float* x  = (const float*)d_in[0];
    const int*   S  = (const int*)d_in[1];
    const float* a  = (const float*)d_in[2];
    const float* b  = (const float*)d_in[3];
    const int*   i3 = (const int*)d_in[4];
    const float* c3 = (const float*)d_in[5];
    const int*   i4 = (const int*)d_in[6];
    const float* c4 = (const float*)d_in[7];
    const int*   i5 = (const int*)d_in[8];
    const float* c5 = (const float*)d_in[9];
    unsigned char* ws = (unsigned char*)d_ws;
    float* out = (float*)d_out;

    prepack<<<16, NT, 0, stream>>>(b, i3, c3, i4, c4, i5, c5, ws);
    poly_main<<<32768 / RPB, NT, 0, stream>>>(x, S, a, ws, out);
}

// Round 7
// 204.882 us; speedup vs baseline: 1.1269x; 1.0255x over previous
//
#include <hip/hip_runtime.h>
#include <hip/hip_fp16.h>
#include <stdint.h>

#define NT 256
#define RPB 32             // rows per block
#define XSTR 80            // bytes per k-slot: 40 halfs (32 rows + 8 pad), 16B-aligned

// ws layout (byte offsets). Tables repacked per-thread-contiguous: slot = (t&63)*8 + (t>>6)
#define WS_P3   0          // 512 x 8B  {o0|o1<<16, o2|c3h<<16}   -> thread ts owns [ts*64 .. ts*64+63]
#define WS_P4   4096       // 512 x 16B {o0|o1, o2|o3, c4h, 0}    -> thread ts owns 128B
#define WS_P5   12288      // 512 x 16B {o0|o1, o2|o3, o4|c5h, 0} -> thread ts owns 128B
#define WS_BUTH 20480      // 64x64 halfs row-major by j: buTh[j*64+i] = (i<j) ? half(b[i][j]) : 0

static __device__ __forceinline__ __half2 H2(unsigned u) {
    return __builtin_bit_cast(__half2, u);
}
static __device__ __forceinline__ unsigned short f2hbits(float f) {
    __half h = __float2half(f);
    return __builtin_bit_cast(unsigned short, h);
}

__global__ void prepack(const float* __restrict__ b,
                        const int* __restrict__ i3, const float* __restrict__ c3,
                        const int* __restrict__ i4, const float* __restrict__ c4,
                        const int* __restrict__ i5, const float* __restrict__ c5,
                        unsigned char* __restrict__ ws)
{
    const int g = blockIdx.x * NT + threadIdx.x;   // 16 x 256 = 4096
    if (g < 4096) {
        int j = g >> 6, i = g & 63;
        float v = (i < j) ? b[i * 64 + j] : 0.0f;  // transposed strict-upper
        ((unsigned short*)(ws + WS_BUTH))[g] = f2hbits(v);
    }
    if (g < 512) {
        const int slot = (g & 63) * 8 + (g >> 6);  // [ts][m] layout
        unsigned o0, o1, o2, o3, o4;
        o0 = (unsigned)i3[3*g+0] * XSTR; o1 = (unsigned)i3[3*g+1] * XSTR; o2 = (unsigned)i3[3*g+2] * XSTR;
        ((uint2*)(ws + WS_P3))[slot] = make_uint2(o0 | (o1 << 16), o2 | ((unsigned)f2hbits(c3[g]) << 16));
        o0 = (unsigned)i4[4*g+0] * XSTR; o1 = (unsigned)i4[4*g+1] * XSTR;
        o2 = (unsigned)i4[4*g+2] * XSTR; o3 = (unsigned)i4[4*g+3] * XSTR;
        ((uint4*)(ws + WS_P4))[slot] = make_uint4(o0 | (o1 << 16), o2 | (o3 << 16), (unsigned)f2hbits(c4[g]), 0u);
        o0 = (unsigned)i5[5*g+0] * XSTR; o1 = (unsigned)i5[5*g+1] * XSTR;
        o2 = (unsigned)i5[5*g+2] * XSTR; o3 = (unsigned)i5[5*g+3] * XSTR;
        o4 = (unsigned)i5[5*g+4] * XSTR;
        ((uint4*)(ws + WS_P5))[slot] = make_uint4(o0 | (o1 << 16), o2 | (o3 << 16), o4 | ((unsigned)f2hbits(c5[g]) << 16), 0u);
    }
}

static __device__ __forceinline__ void qfma(__half2 bb, uint4 xk, __half2 d[4]) {
    d[0] = __hfma2(bb, H2(xk.x), d[0]);
    d[1] = __hfma2(bb, H2(xk.y), d[1]);
    d[2] = __hfma2(bb, H2(xk.z), d[2]);
    d[3] = __hfma2(bb, H2(xk.w), d[3]);
}
static __device__ __forceinline__ void pmul(const uint4& a, __half2 p[4]) {
    p[0] = __hmul2(p[0], H2(a.x));
    p[1] = __hmul2(p[1], H2(a.y));
    p[2] = __hmul2(p[2], H2(a.z));
    p[3] = __hmul2(p[3], H2(a.w));
}
static __device__ __forceinline__ void pacc(__half2 c2, const __half2 p[4], __half2 acc[4]) {
    acc[0] = __hfma2(c2, p[0], acc[0]);
    acc[1] = __hfma2(c2, p[1], acc[1]);
    acc[2] = __hfma2(c2, p[2], acc[2]);
    acc[3] = __hfma2(c2, p[3], acc[3]);
}

// LDS: 5120 (xS fp16) + 512 (red) = 5632 B. 1024 blocks -> 4 blocks/CU, 16 waves/CU.
__global__ __launch_bounds__(NT, 4)
void poly_main(const float* __restrict__ x, const int* __restrict__ S,
               const float* __restrict__ a,
               const unsigned char* __restrict__ ws, float* __restrict__ out)
{
    __shared__ __align__(16) __half xS[64 * 40];   // [k][32 rows (fp16) + 8 pad]
    __shared__ float red[4][4][8];                 // [wave][rg][row-in-group]

    const int tid  = threadIdx.x;
    const int row0 = blockIdx.x * RPB;

    const int rg = tid & 3;
    const int ts = tid >> 2;

    // ---- batched register preload of this thread's table entries (independent VMEM) ----
    uint2 e3[8];
    uint4 e4[8], e5[8], bw[8];
    {
        const uint4* s3 = (const uint4*)(ws + WS_P3 + ts * 64);
        #pragma unroll
        for (int i = 0; i < 4; ++i) ((uint4*)e3)[i] = s3[i];
        const uint4* s4 = (const uint4*)(ws + WS_P4 + ts * 128);
        #pragma unroll
        for (int i = 0; i < 8; ++i) e4[i] = s4[i];
        const uint4* s5 = (const uint4*)(ws + WS_P5 + ts * 128);
        #pragma unroll
        for (int i = 0; i < 8; ++i) e5[i] = s5[i];
        const uint4* sb = (const uint4*)(ws + WS_BUTH + ts * 128);
        #pragma unroll
        for (int i = 0; i < 8; ++i) bw[i] = sb[i];
    }
    const float av = a[ts];

    // ---- gather + fp16 pack: lane k, wave q loads rows q*8..q*8+7 ----
    {
        const int k = tid & 63, q = tid >> 6;
        const int sk = S[k];
        const float* xc = x + (size_t)row0 * 1024 + sk;
        float v[8];
        #pragma unroll
        for (int m = 0; m < 8; ++m) v[m] = xc[(size_t)(q * 8 + m) * 1024];
        uint4 pk;
        pk.x = __builtin_bit_cast(unsigned, __floats2half2_rn(v[0], v[1]));
        pk.y = __builtin_bit_cast(unsigned, __floats2half2_rn(v[2], v[3]));
        pk.z = __builtin_bit_cast(unsigned, __floats2half2_rn(v[4], v[5]));
        pk.w = __builtin_bit_cast(unsigned, __floats2half2_rn(v[6], v[7]));
        *(uint4*)((char*)xS + k * XSTR + q * 16) = pk;
    }
    __syncthreads();

    // ---- compute: rg owns rows rg*8..rg*8+7 (4 half2), ts = j / term slice (0..63) ----
    const char* xb = (const char*)xS + rg * 16;

    // quad (triangular): d = sum_{i<ts} buT[ts][i] * x_i ; preloaded bw, masked full unroll
    __half2 d[4] = {H2(0u), H2(0u), H2(0u), H2(0u)};
    {
        const int nii = (ts + 7) >> 3;             // 1..8; varies <=1 within a wave
        #pragma unroll
        for (int g = 0; g < 8; ++g) {
            if (g < nii) {
                uint4 w4 = bw[g];
                const char* xkb = xb + g * 8 * XSTR;
                unsigned pw[4] = {w4.x, w4.y, w4.z, w4.w};
                #pragma unroll
                for (int p = 0; p < 4; ++p) {
                    __half2 blo = __half2half2(__ushort_as_half((unsigned short)(pw[p] & 0xFFFFu)));
                    __half2 bhi = __half2half2(__ushort_as_half((unsigned short)(pw[p] >> 16)));
                    uint4 x0 = *(const uint4*)(xkb + (2 * p + 0) * XSTR);
                    uint4 x1 = *(const uint4*)(xkb + (2 * p + 1) * XSTR);
                    qfma(blo, x0, d);
                    qfma(bhi, x1, d);
                }
            }
        }
    }
    __half2 acc[4];
    {
        __half2 a2 = __half2half2(__float2half(av));
        uint4 xj = *(const uint4*)(xb + ts * XSTR);
        acc[0] = __hmul2(__hadd2(a2, d[0]), H2(xj.x));
        acc[1] = __hmul2(__hadd2(a2, d[1]), H2(xj.y));
        acc[2] = __hmul2(__hadd2(a2, d[2]), H2(xj.z));
        acc[3] = __hmul2(__hadd2(a2, d[3]), H2(xj.w));
    }

    // ---- monomials: entries preloaded in registers, loops are pure LDS+VALU ----
    #pragma unroll
    for (int m = 0; m < 8; ++m) {
        uint2 p = e3[m];
        uint4 v0 = *(const uint4*)(xb + (p.x & 0xFFFFu));
        uint4 v1 = *(const uint4*)(xb + (p.x >> 16));
        uint4 v2 = *(const uint4*)(xb + (p.y & 0xFFFFu));
        __half2 pr[4] = {H2(v0.x), H2(v0.y), H2(v0.z), H2(v0.w)};
        pmul(v1, pr);
        pmul(v2, pr);
        pacc(__half2half2(__ushort_as_half((unsigned short)(p.y >> 16))), pr, acc);
    }
    #pragma unroll
    for (int m = 0; m < 8; ++m) {
        uint4 p = e4[m];
        uint4 v0 = *(const uint4*)(xb + (p.x & 0xFFFFu));
        uint4 v1 = *(const uint4*)(xb + (p.x >> 16));
        uint4 v2 = *(const uint4*)(xb + (p.y & 0xFFFFu));
        uint4 v3 = *(const uint4*)(xb + (p.y >> 16));
        __half2 pr[4] = {H2(v0.x), H2(v0.y), H2(v0.z), H2(v0.w)};
        pmul(v1, pr);
        pmul(v2, pr);
        pmul(v3, pr);
        pacc(__half2half2(__ushort_as_half((unsigned short)(p.z & 0xFFFFu))), pr, acc);
    }
    #pragma unroll
    for (int m = 0; m < 8; ++m) {
        uint4 p = e5[m];
        uint4 v0 = *(const uint4*)(xb + (p.x & 0xFFFFu));
        uint4 v1 = *(const uint4*)(xb + (p.x >> 16));
        uint4 v2 = *(const uint4*)(xb + (p.y & 0xFFFFu));
        uint4 v3 = *(const uint4*)(xb + (p.y >> 16));
        uint4 v4 = *(const uint4*)(xb + (p.z & 0xFFFFu));
        __half2 pr[4] = {H2(v0.x), H2(v0.y), H2(v0.z), H2(v0.w)};
        pmul(v1, pr);
        pmul(v2, pr);
        pmul(v3, pr);
        pmul(v4, pr);
        pacc(__half2half2(__ushort_as_half((unsigned short)(p.z >> 16))), pr, acc);
    }

    // ---- reduce 16 ts-partials per wave in fp32, then cross-wave via LDS ----
    float f[8];
    #pragma unroll
    for (int e = 0; e < 4; ++e) {
        f[2 * e]     = __low2float(acc[e]);
        f[2 * e + 1] = __high2float(acc[e]);
    }
    #pragma unroll
    for (int mask = 4; mask <= 32; mask <<= 1) {
        #pragma unroll
        for (int r = 0; r < 8; ++r) f[r] += __shfl_xor(f[r], mask, 64);
    }
    const int w = tid >> 6, lane = tid & 63;
    if (lane < 4) {
        #pragma unroll
        for (int r = 0; r < 8; ++r) red[w][lane][r] = f[r];
    }
    __syncthreads();
    if (tid < 32) {
        int g = tid >> 3, e = tid & 7;
        out[row0 + tid] = red[0][g][e] + red[1][g][e] + red[2][g][e] + red[3][g][e];
    }
}

extern "C" void kernel_launch(void* const* d_in, const int* in_sizes, int n_in,
                              void* d_out, int out_size, void* d_ws, size_t ws_size,
                              hipStream_t stream) {
    const float* x  = (const float*)d_in[0];
    const int*   S  = (const int*)d_in[1];
    const float* a  = (const float*)d_in[2];
    const float* b  = (const float*)d_in[3];
    const int*   i3 = (const int*)d_in[4];
    const float* c3 = (const float*)d_in[5];
    const int*   i4 = (const int*)d_in[6];
    const float* c4 = (const float*)d_in[7];
    const int*   i5 = (const int*)d_in[8];
    const float* c5 = (const float*)d_in[9];
    unsigned char* ws = (unsigned char*)d_ws;
    float* out = (float*)d_out;

    prepack<<<16, NT, 0, stream>>>(b, i3, c3, i4, c4, i5, c5, ws);
    poly_main<<<32768 / RPB, NT, 0, stream>>>(x, S, a, ws, out);
}